// Round 7
// baseline (94.160 us; speedup 1.0000x reference)
//
#include <hip/hip_runtime.h>
#include <hip/hip_bf16.h>
#include <cstddef>
#include <cstdint>

#define BATCH 131072
#define HOFF ((size_t)BATCH * 66)

typedef __attribute__((ext_vector_type(8))) short short8;
typedef __attribute__((ext_vector_type(4))) short short4v;
typedef __attribute__((ext_vector_type(4))) float f32x4;

typedef const __attribute__((address_space(1))) unsigned int* gas_t;
typedef __attribute__((address_space(3))) unsigned int* las_t;

// d_ws layout (bf16 elems): fuse [128][104] (= two 64x104 half-units, 6656 shorts each)
//   | 16 GRU units (48 rows x 136, padded to 6656) | 10 head units (32 rows x 136, padded to 4608)
#define WS_GRU   13312
#define WS_HEAD  119808
#define WS_ELEMS 165888

#define MFMA(a,b,c) __builtin_amdgcn_mfma_f32_16x16x32_bf16((a),(b),(c),0,0,0)

__device__ __forceinline__ short f2bf(float x) {
    // HW RNE convert (v_cvt_pk_bf16_f32 via compiler; m240: scalar cast is the fast path)
    __hip_bfloat16 b = __float2bfloat16(x);
    return __builtin_bit_cast(short, b);
}
__device__ __forceinline__ float bf2f(short s) {
    unsigned u = ((unsigned)(unsigned short)s) << 16;
    return __builtin_bit_cast(float, u);
}
__device__ __forceinline__ float fsigmoid(float x) { return __builtin_amdgcn_rcpf(1.0f + __expf(-x)); }
__device__ __forceinline__ float ftanh(float x)    { return 1.0f - 2.0f * __builtin_amdgcn_rcpf(1.0f + __expf(2.0f * x)); }

__device__ __forceinline__ short8 packbf(f32x4 a, f32x4 b) {
    short8 r;
    r[0]=f2bf(a[0]); r[1]=f2bf(a[1]); r[2]=f2bf(a[2]); r[3]=f2bf(a[3]);
    r[4]=f2bf(b[0]); r[5]=f2bf(b[1]); r[6]=f2bf(b[2]); r[7]=f2bf(b[3]);
    return r;
}

// async global->LDS: linear dest, 16B/lane; 512-thread chunking, tail guards wave-uniform
// (1664%512=128 -> waves 0-1; 832%512=320 -> waves 0-4; 576%512=64 -> wave 0)
template<int NCH>
__device__ __forceinline__ void stage_lds(const short* __restrict__ src, short* dst, int t) {
    constexpr int NP = (NCH + 511) / 512;
    #pragma unroll
    for (int k = 0; k < NP; ++k) {
        int c = t + 512 * k;
        if ((NCH % 512 == 0) || c < NCH)
            __builtin_amdgcn_global_load_lds((gas_t)(const void*)(src + (size_t)c * 8),
                                             (las_t)(void*)(dst + (size_t)c * 8), 16, 0, 0);
    }
}

// ---------------- prep: f32 weights -> bf16 units in d_ws ----------------
extern "C" __global__ void prep_weights(const float* __restrict__ fuse_W,
                                        const float* __restrict__ W_ih, const float* __restrict__ W_hh,
                                        const float* __restrict__ ns_W1, const float* __restrict__ ns_W2,
                                        const float* __restrict__ rw_W1, const float* __restrict__ dn_W1,
                                        short* __restrict__ ws) {
    int i = blockIdx.x * 256 + threadIdx.x;
    if (i >= WS_ELEMS) return;
    float v = 0.f;
    if (i < WS_GRU) {                       // fuse: [128][104], K padded 80->104
        int j = i / 104, k = i % 104;
        if (k < 80) v = fuse_W[j*80 + k];
    } else if (i < WS_HEAD) {
        int g = (i - WS_GRU) / 6656, e = (i - WS_GRU) % 6656;
        int r = e / 136, k = e % 136;
        if (r < 48 && k < 128) {
            int j = g >> 1;
            const float* W = (g & 1) ? W_hh : W_ih;
            int gate = r >> 4, rr = r & 15;
            v = W[(size_t)(gate*128 + j*16 + rr)*128 + k];
        }
    } else {                                // head units: 0-3 ns_W1, 4-5 ns_W2, 6-7 rw_W1, 8-9 dn_W1
        int h = (i - WS_HEAD) / 4608, e = (i - WS_HEAD) % 4608;
        int r = e / 136, k = e % 136;
        if (r < 32 && k < 128) {
            const float* W; int rb;
            if (h < 4)      { W = ns_W1; rb = h*32; }
            else if (h < 6) { W = ns_W2; rb = (h-4)*32; }
            else if (h < 8) { W = rw_W1; rb = (h-6)*32; }
            else            { W = dn_W1; rb = (h-8)*32; }
            v = W[(size_t)(rb + r)*128 + k];
        }
    }
    ws[i] = f2bf(v);
}

// head GEMM: 2 subs of 16 output cols from a weight half, into strip SP
#define HEAD_GEMM(FRAG, BIAS, Q, HALFOFF, SP, RELU) do {                                   \
    _Pragma("unroll") for (int sub = 0; sub < 2; ++sub) {                                  \
        float bb = (BIAS)[(Q)*32 + sub*16 + lo];                                           \
        f32x4 a0 = zz4, a1 = zz4;                                                          \
        _Pragma("unroll") for (int kt = 0; kt < 4; ++kt) {                                 \
            short8 Bf = *(const short8*)&smem[(HALFOFF) + (sub*16+lo)*136 + kt*32 + hi*8]; \
            a0 = MFMA((FRAG)[0][kt], Bf, a0); a1 = MFMA((FRAG)[1][kt], Bf, a1); }          \
        _Pragma("unroll") for (int e = 0; e < 4; ++e) {                                    \
            float v0 = a0[e] + bb, v1 = a1[e] + bb;                                        \
            if (RELU) { v0 = fmaxf(v0, 0.f); v1 = fmaxf(v1, 0.f); }                        \
            (SP)[(4*hi+e)*40 + sub*16 + lo]      = f2bf(v0);                               \
            (SP)[(16+4*hi+e)*40 + sub*16 + lo]   = f2bf(v1); }                             \
    } } while (0)

#define AFRAG_READ(DST, Q, SP) do {                                    \
    (DST)[0][Q] = *(const short8*)&(SP)[lo*40 + hi*8];                 \
    (DST)[1][Q] = *(const short8*)&(SP)[(16+lo)*40 + hi*8]; } while (0)

// ---------------- main fused kernel: 512 threads (8 waves x 32 rows), grid 512 ----------------
extern "C" __global__ __launch_bounds__(512, 2)
void gru_mfma(const float* __restrict__ z_t, const int* __restrict__ action,
              const float* __restrict__ hidden, const float* __restrict__ embed,
              const float* __restrict__ fuse_b,
              const float* __restrict__ b_ih, const float* __restrict__ b_hh,
              const float* __restrict__ ns_b1, const float* __restrict__ ns_b2,
              const float* __restrict__ rw_b1, const float* __restrict__ rw_W2, const float* __restrict__ rw_b2,
              const float* __restrict__ dn_b1, const float* __restrict__ dn_W2, const float* __restrict__ dn_b2,
              const short* __restrict__ ws, float* out)
{
    // [0,13312): weight double-buffer (2 x 6656). [13312,33792): 8 waves x 2 strips x [32][40]
    __shared__ __align__(16) short smem[33792];   // 67584 B -> 2 blocks/CU, 16 waves/CU @ <=128 VGPR

    const int t    = threadIdx.x;
    const int lane = t & 63;
    const int w    = t >> 6;
    const int lo   = lane & 15;
    const int hi   = lane >> 4;
    const int R    = blockIdx.x * 256 + w * 32;   // wave's first batch row
    short* const S0 = &smem[13312 + w * 2560];
    short* const S1 = S0 + 1280;

    const f32x4 zz4 = {0.f, 0.f, 0.f, 0.f};

    auto store_hnew_strip = [&](const short* SP, int kt) {
        #pragma unroll
        for (int v = 0; v < 4; ++v) {
            int idx = v*64 + lane;
            int r = idx >> 3, c = (idx & 7) * 4;
            short4v s = *(const short4v*)&SP[r*40 + c];
            f32x4 f = { bf2f(s[0]), bf2f(s[1]), bf2f(s[2]), bf2f(s[3]) };
            *(f32x4*)&out[HOFF + (size_t)(R + r)*128 + kt*32 + c] = f;
        }
    };
    auto store_z_strip = [&](const short* SP, int q) {
        #pragma unroll
        for (int v = 0; v < 4; ++v) {
            int idx = v*64 + lane;
            int r = idx >> 3, c = (idx & 7) * 4;
            short4v s = *(const short4v*)&SP[r*40 + c];
            f32x4 f = { bf2f(s[0]), bf2f(s[1]), bf2f(s[2]), bf2f(s[3]) };
            *(f32x4*)&out[(size_t)(R + r)*64 + q*32 + c] = f;
        }
    };
    auto head1_dot = [&](const float* W2, float b2) -> float {
        int rr = lane & 31;
        float acc = b2;
        #pragma unroll
        for (int kk = 0; kk < 64; kk += 8) {
            const short* SP = (kk < 32) ? S0 : S1;
            short8 s = *(const short8*)&SP[rr*40 + (kk & 31)];
            f32x4 w0 = *(const f32x4*)&W2[kk];
            f32x4 w1 = *(const f32x4*)&W2[kk+4];
            acc += bf2f(s[0])*w0[0] + bf2f(s[1])*w0[1] + bf2f(s[2])*w0[2] + bf2f(s[3])*w0[3]
                 + bf2f(s[4])*w1[0] + bf2f(s[5])*w1[1] + bf2f(s[6])*w1[2] + bf2f(s[7])*w1[3];
        }
        return acc;
    };

    // ---- issue fuse-weight staging (f0 -> half0, f1 -> half1, contiguous) ----
    stage_lds<1664>(ws, &smem[0], t);

    // ---- A-fragments direct from global, f32 -> bf16 ----
    short8 fa[2][3];
    short8 ha[2][4];
    #pragma unroll
    for (int rt = 0; rt < 2; ++rt) {
        const int row = R + rt*16 + lo;
        #pragma unroll
        for (int kt = 0; kt < 2; ++kt) {
            f32x4 p0 = *(const f32x4*)&z_t[(size_t)row*64 + kt*32 + hi*8];
            f32x4 p1 = *(const f32x4*)&z_t[(size_t)row*64 + kt*32 + hi*8 + 4];
            fa[rt][kt] = packbf(p0, p1);
        }
        if (hi < 2) {
            int a = action[row];
            f32x4 e0 = *(const f32x4*)&embed[a*16 + hi*8];
            f32x4 e1 = *(const f32x4*)&embed[a*16 + hi*8 + 4];
            fa[rt][2] = packbf(e0, e1);
        } else {
            short8 z8 = {0,0,0,0,0,0,0,0};
            fa[rt][2] = z8;
        }
        #pragma unroll
        for (int kt = 0; kt < 4; ++kt) {
            f32x4 p0 = *(const f32x4*)&hidden[(size_t)row*128 + kt*32 + hi*8];
            f32x4 p1 = *(const f32x4*)&hidden[(size_t)row*128 + kt*32 + hi*8 + 4];
            ha[rt][kt] = packbf(p0, p1);
        }
    }
    float fbv[8];
    #pragma unroll
    for (int ct = 0; ct < 8; ++ct) fbv[ct] = fuse_b[ct*16 + lo];

    // ---- h0 D-layout values via strip transposes (wave-private, no barrier) ----
    unsigned h0d[8][2][2];
    #pragma unroll
    for (int kt = 0; kt < 4; ++kt) {
        short* SP = (kt & 1) ? S1 : S0;
        *(short8*)&SP[lo*40 + hi*8]        = ha[0][kt];
        *(short8*)&SP[(16 + lo)*40 + hi*8] = ha[1][kt];
        #pragma unroll
        for (int c = 0; c < 2; ++c) {
            int j = 2*kt + c;
            #pragma unroll
            for (int rt = 0; rt < 2; ++rt)
                #pragma unroll
                for (int p = 0; p < 2; ++p) {
                    unsigned a = (unsigned short)SP[(rt*16 + 4*hi + 2*p    )*40 + c*16 + lo];
                    unsigned b = (unsigned short)SP[(rt*16 + 4*hi + 2*p + 1)*40 + c*16 + lo];
                    h0d[j][rt][p] = a | (b << 16);
                }
        }
    }
    __syncthreads();                       // fuse weights resident

    // ---- fuse part 0: ct 0..3 (kt 0,1) from half0 ----
    short8 xa[2][4];
    #pragma unroll
    for (int kt = 0; kt < 2; ++kt) {
        short* SP = (kt & 1) ? S1 : S0;
        #pragma unroll
        for (int c = 0; c < 2; ++c) {
            int ct = kt*2 + c;
            f32x4 a0 = zz4, a1 = zz4;
            #pragma unroll
            for (int fk = 0; fk < 3; ++fk) {
                short8 B = *(const short8*)&smem[(ct*16 + lo)*104 + fk*32 + hi*8];
                a0 = MFMA(fa[0][fk], B, a0);
                a1 = MFMA(fa[1][fk], B, a1);
            }
            #pragma unroll
            for (int e = 0; e < 4; ++e) {
                SP[(4*hi + e)*40 + c*16 + lo]      = f2bf(fmaxf(a0[e] + fbv[ct], 0.f));
                SP[(16 + 4*hi + e)*40 + c*16 + lo] = f2bf(fmaxf(a1[e] + fbv[ct], 0.f));
            }
        }
        AFRAG_READ(xa, kt, SP);
    }
    __syncthreads();                       // all waves done with half0 (fuse f0)
    stage_lds<832>(ws + WS_GRU, &smem[0], t);   // GRU unit 0 -> half0

    // ---- fuse part 1: ct 4..7 (kt 2,3) from half1 ----
    #pragma unroll
    for (int kt = 2; kt < 4; ++kt) {
        short* SP = (kt & 1) ? S1 : S0;
        #pragma unroll
        for (int c = 0; c < 2; ++c) {
            int ct = kt*2 + c;
            f32x4 a0 = zz4, a1 = zz4;
            #pragma unroll
            for (int fk = 0; fk < 3; ++fk) {
                short8 B = *(const short8*)&smem[6656 + ((ct - 4)*16 + lo)*104 + fk*32 + hi*8];
                a0 = MFMA(fa[0][fk], B, a0);
                a1 = MFMA(fa[1][fk], B, a1);
            }
            #pragma unroll
            for (int e = 0; e < 4; ++e) {
                SP[(4*hi + e)*40 + c*16 + lo]      = f2bf(fmaxf(a0[e] + fbv[ct], 0.f));
                SP[(16 + 4*hi + e)*40 + c*16 + lo] = f2bf(fmaxf(a1[e] + fbv[ct], 0.f));
            }
        }
        AFRAG_READ(xa, kt, SP);
    }
    __syncthreads();                       // unit 0 resident; half1 free

    // ---- GRU: fully unrolled; phase A = gi (W_ih), phase B = gh (W_hh) + elementwise ----
    short8 hfa[2][4];
    #pragma unroll
    for (int j = 0; j < 8; ++j) {
        // phase A: stage unit 2j+1 -> half1; capture+store completed h_new strips; gi from half0
        stage_lds<832>(ws + WS_GRU + (size_t)(2*j + 1)*6656, &smem[6656], t);
        if (j == 2) { AFRAG_READ(hfa, 0, S0); store_hnew_strip(S0, 0); }
        if (j == 4) { AFRAG_READ(hfa, 1, S1); store_hnew_strip(S1, 1); }
        const int j0 = j * 16;
        const float bir = b_ih[j0+lo], biz = b_ih[128+j0+lo], bin = b_ih[256+j0+lo];
        const float bhr = b_hh[j0+lo], bhz = b_hh[128+j0+lo], bhn = b_hh[256+j0+lo];
        f32x4 accI[3][2];
        #pragma unroll
        for (int g = 0; g < 3; ++g) {
            accI[g][0] = zz4; accI[g][1] = zz4;
            #pragma unroll
            for (int kt = 0; kt < 4; ++kt) {
                short8 B = *(const short8*)&smem[(g*16 + lo)*136 + kt*32 + hi*8];
                accI[g][0] = MFMA(xa[0][kt], B, accI[g][0]);
                accI[g][1] = MFMA(xa[1][kt], B, accI[g][1]);
            }
        }
        __syncthreads();

        // phase B: stage next -> half0; gh from half1; elementwise -> h_new strip
        if (j < 7) stage_lds<832>(ws + WS_GRU + (size_t)(2*j + 2)*6656, &smem[0], t);
        else       stage_lds<576>(ws + WS_HEAD, &smem[0], t);
        f32x4 accH[3][2];
        #pragma unroll
        for (int g = 0; g < 3; ++g) {
            accH[g][0] = zz4; accH[g][1] = zz4;
            #pragma unroll
            for (int kt = 0; kt < 4; ++kt) {
                short8 B = *(const short8*)&smem[6656 + (g*16 + lo)*136 + kt*32 + hi*8];
                accH[g][0] = MFMA(ha[0][kt], B, accH[g][0]);
                accH[g][1] = MFMA(ha[1][kt], B, accH[g][1]);
            }
        }
        {
            short* HP = ((j >> 1) & 1) ? S1 : S0;
            #pragma unroll
            for (int rt = 0; rt < 2; ++rt) {
                #pragma unroll
                for (int p = 0; p < 2; ++p) {
                    unsigned hp = h0d[j][rt][p];
                    float h0a = bf2f((short)(hp & 0xffffu));
                    float h0b = bf2f((short)(hp >> 16));
                    int e = 2*p;
                    {
                        float rg = fsigmoid(accI[0][rt][e] + bir + accH[0][rt][e] + bhr);
                        float zg = fsigmoid(accI[1][rt][e] + biz + accH[1][rt][e] + bhz);
                        float ng = ftanh(accI[2][rt][e] + bin + rg*(accH[2][rt][e] + bhn));
                        HP[(rt*16 + 4*hi + e)*40 + (j&1)*16 + lo] = f2bf((1.f - zg)*ng + zg*h0a);
                    }
                    {
                        float rg = fsigmoid(accI[0][rt][e+1] + bir + accH[0][rt][e+1] + bhr);
                        float zg = fsigmoid(accI[1][rt][e+1] + biz + accH[1][rt][e+1] + bhz);
                        float ng = ftanh(accI[2][rt][e+1] + bin + rg*(accH[2][rt][e+1] + bhn));
                        HP[(rt*16 + 4*hi + e+1)*40 + (j&1)*16 + lo] = f2bf((1.f - zg)*ng + zg*h0b);
                    }
                }
            }
        }
        __syncthreads();
    }

    // ---- heads (strips recycled per 32-col group) ----
    short8 ta[2][4];

    // u16: finish h_new (strips kt2/kt3 -> hfa + store), ns1 q0 (half0)
    stage_lds<576>(ws + WS_HEAD + 4608, &smem[6656], t);
    AFRAG_READ(hfa, 2, S0); store_hnew_strip(S0, 2);
    AFRAG_READ(hfa, 3, S1); store_hnew_strip(S1, 3);
    HEAD_GEMM(hfa, ns_b1, 0, 0, S0, true);
    AFRAG_READ(ta, 0, S0);
    __syncthreads();

    // u17: ns1 q1 (half1)
    stage_lds<576>(ws + WS_HEAD + 2*4608, &smem[0], t);
    HEAD_GEMM(hfa, ns_b1, 1, 6656, S1, true);
    AFRAG_READ(ta, 1, S1);
    __syncthreads();

    // u18: ns1 q2 (half0)
    stage_lds<576>(ws + WS_HEAD + 3*4608, &smem[6656], t);
    HEAD_GEMM(hfa, ns_b1, 2, 0, S0, true);
    AFRAG_READ(ta, 2, S0);
    __syncthreads();

    // u19: ns1 q3 (half1)
    stage_lds<576>(ws + WS_HEAD + 4*4608, &smem[0], t);
    HEAD_GEMM(hfa, ns_b1, 3, 6656, S1, true);
    AFRAG_READ(ta, 3, S1);
    __syncthreads();

    // u20: ns2 q0 (half0) -> z_next cols 0..31
    stage_lds<576>(ws + WS_HEAD + 5*4608, &smem[6656], t);
    HEAD_GEMM(ta, ns_b2, 0, 0, S0, false);
    store_z_strip(S0, 0);
    __syncthreads();

    // u21: ns2 q1 (half1) -> z_next cols 32..63
    stage_lds<576>(ws + WS_HEAD + 6*4608, &smem[0], t);
    HEAD_GEMM(ta, ns_b2, 1, 6656, S1, false);
    store_z_strip(S1, 1);
    __syncthreads();

    // u22: rw1 q0 (half0) -> t2r cols 0..31
    stage_lds<576>(ws + WS_HEAD + 7*4608, &smem[6656], t);
    HEAD_GEMM(hfa, rw_b1, 0, 0, S0, true);
    __syncthreads();

    // u23: rw1 q1 (half1) -> t2r cols 32..63
    stage_lds<576>(ws + WS_HEAD + 8*4608, &smem[0], t);
    HEAD_GEMM(hfa, rw_b1, 1, 6656, S1, true);
    __syncthreads();

    // u24: reward dot (t2r strips), then dn1 q0 (half0) -> t2d cols 0..31
    stage_lds<576>(ws + WS_HEAD + 9*4608, &smem[6656], t);
    {
        float racc = head1_dot(rw_W2, rw_b2[0]);
        if (lane < 32) out[(size_t)BATCH*64 + R + (lane & 31)] = racc;
    }
    HEAD_GEMM(hfa, dn_b1, 0, 0, S0, true);
    __syncthreads();

    // u25: dn1 q1 (half1) -> t2d cols 32..63; done dot
    HEAD_GEMM(hfa, dn_b1, 1, 6656, S1, true);
    {
        float dacc = head1_dot(dn_W2, dn_b2[0]);
        if (lane < 32) out[(size_t)BATCH*65 + R + (lane & 31)] = dacc;
    }
}

extern "C" void kernel_launch(void* const* d_in, const int* in_sizes, int n_in,
                              void* d_out, int out_size, void* d_ws, size_t ws_size,
                              hipStream_t stream) {
    const float* z_t    = (const float*)d_in[0];
    const int*   action = (const int*)  d_in[1];
    const float* hidden = (const float*)d_in[2];
    const float* embed  = (const float*)d_in[3];
    const float* fuse_W = (const float*)d_in[4];
    const float* fuse_b = (const float*)d_in[5];
    const float* W_ih   = (const float*)d_in[6];
    const float* W_hh   = (const float*)d_in[7];
    const float* b_ih   = (const float*)d_in[8];
    const float* b_hh   = (const float*)d_in[9];
    const float* ns_W1  = (const float*)d_in[10];
    const float* ns_b1  = (const float*)d_in[11];
    const float* ns_W2  = (const float*)d_in[12];
    const float* ns_b2  = (const float*)d_in[13];
    const float* rw_W1  = (const float*)d_in[14];
    const float* rw_b1  = (const float*)d_in[15];
    const float* rw_W2  = (const float*)d_in[16];
    const float* rw_b2  = (const float*)d_in[17];
    const float* dn_W1  = (const float*)d_in[18];
    const float* dn_b1  = (const float*)d_in[19];
    const float* dn_W2  = (const float*)d_in[20];
    const float* dn_b2  = (const float*)d_in[21];
    float* out = (float*)d_out;
    short* ws  = (short*)d_ws;

    hipLaunchKernelGGL(prep_weights, dim3((WS_ELEMS + 255) / 256), dim3(256), 0, stream,
                       fuse_W, W_ih, W_hh, ns_W1, ns_W2, rw_W1, dn_W1, ws);

    hipLaunchKernelGGL(gru_mfma, dim3(BATCH / 256), dim3(512), 0, stream,
                       z_t, action, hidden, embed,
                       fuse_b, b_ih, b_hh, ns_b1, ns_b2,
                       rw_b1, rw_W2, rw_b2, dn_b1, dn_W2, dn_b2,
                       ws, out);
}

// Round 8
// 83.722 us; speedup vs baseline: 1.1247x; 1.1247x over previous
//
#include <hip/hip_runtime.h>
#include <hip/hip_bf16.h>
#include <cstddef>
#include <cstdint>

#define BATCH 131072
#define HOFF ((size_t)BATCH * 66)

typedef __attribute__((ext_vector_type(8))) short short8;
typedef __attribute__((ext_vector_type(4))) short short4v;
typedef __attribute__((ext_vector_type(4))) float f32x4;

typedef const __attribute__((address_space(1))) unsigned int* gas_t;
typedef __attribute__((address_space(3))) unsigned int* las_t;

// d_ws layout (bf16 elems): fuse [128][104] | 16 GRU units ([48][136] = 6656)
//                           | 10 head units ([32][136] = 4352, tightly packed)
#define WS_GRU   13312
#define WS_HEAD  (13312 + 16*6656)          // 119808
#define WS_ELEMS (WS_HEAD + 10*4352)        // 163328

// smem layout (shorts): F fuse [0,13312) | G units [13312,66560) | strips [66560,76800)
#define G_BASE   13312
#define STR_BASE 66560

#define MFMA(a,b,c) __builtin_amdgcn_mfma_f32_16x16x32_bf16((a),(b),(c),0,0,0)

__device__ __forceinline__ short f2bf(float x) {
    __hip_bfloat16 b = __float2bfloat16(x);
    return __builtin_bit_cast(short, b);
}
__device__ __forceinline__ float bf2f(short s) {
    unsigned u = ((unsigned)(unsigned short)s) << 16;
    return __builtin_bit_cast(float, u);
}
__device__ __forceinline__ float fsigmoid(float x) { return __builtin_amdgcn_rcpf(1.0f + __expf(-x)); }
__device__ __forceinline__ float ftanh(float x)    { return 1.0f - 2.0f * __builtin_amdgcn_rcpf(1.0f + __expf(2.0f * x)); }

__device__ __forceinline__ short8 packbf(f32x4 a, f32x4 b) {
    short8 r;
    r[0]=f2bf(a[0]); r[1]=f2bf(a[1]); r[2]=f2bf(a[2]); r[3]=f2bf(a[3]);
    r[4]=f2bf(b[0]); r[5]=f2bf(b[1]); r[6]=f2bf(b[2]); r[7]=f2bf(b[3]);
    return r;
}

// async global->LDS: linear dest, 16B/lane; 512-thread chunking, tail guards wave-uniform
// (1664: t<128 waves0-1; 6656: exact; 5440: t<320 waves0-4)
template<int NCH>
__device__ __forceinline__ void stage_lds(const short* __restrict__ src, short* dst, int t) {
    constexpr int NP = (NCH + 511) / 512;
    #pragma unroll
    for (int k = 0; k < NP; ++k) {
        int c = t + 512 * k;
        if ((NCH % 512 == 0) || c < NCH)
            __builtin_amdgcn_global_load_lds((gas_t)(const void*)(src + (size_t)c * 8),
                                             (las_t)(void*)(dst + (size_t)c * 8), 16, 0, 0);
    }
}

// ---------------- prep: f32 weights -> bf16 units in d_ws ----------------
extern "C" __global__ void prep_weights(const float* __restrict__ fuse_W,
                                        const float* __restrict__ W_ih, const float* __restrict__ W_hh,
                                        const float* __restrict__ ns_W1, const float* __restrict__ ns_W2,
                                        const float* __restrict__ rw_W1, const float* __restrict__ dn_W1,
                                        short* __restrict__ ws) {
    int i = blockIdx.x * 256 + threadIdx.x;
    if (i >= WS_ELEMS) return;
    float v = 0.f;
    if (i < WS_GRU) {                       // fuse: [128][104], K padded 80->104
        int j = i / 104, k = i % 104;
        if (k < 80) v = fuse_W[j*80 + k];
    } else if (i < WS_HEAD) {               // GRU units [48][136]
        int g = (i - WS_GRU) / 6656, e = (i - WS_GRU) % 6656;
        int r = e / 136, k = e % 136;
        if (r < 48 && k < 128) {
            int j = g >> 1;
            const float* W = (g & 1) ? W_hh : W_ih;
            int gate = r >> 4, rr = r & 15;
            v = W[(size_t)(gate*128 + j*16 + rr)*128 + k];
        }
    } else {                                // head units [32][136]: 0-3 ns_W1, 4-5 ns_W2, 6-7 rw_W1, 8-9 dn_W1
        int h = (i - WS_HEAD) / 4352, e = (i - WS_HEAD) % 4352;
        int r = e / 136, k = e % 136;
        if (k < 128) {
            const float* W; int rb;
            if (h < 4)      { W = ns_W1; rb = h*32; }
            else if (h < 6) { W = ns_W2; rb = (h-4)*32; }
            else if (h < 8) { W = rw_W1; rb = (h-6)*32; }
            else            { W = dn_W1; rb = (h-8)*32; }
            v = W[(size_t)(rb + r)*128 + k];
        }
    }
    ws[i] = f2bf(v);
}

// head GEMM: 2 subs of 16 output cols from unit at UBASE, into strip S
#define HEAD_GEMM(FRAG, BIAS, Q, UBASE, RELU) do {                                          \
    _Pragma("unroll") for (int sub = 0; sub < 2; ++sub) {                                   \
        float bb = (BIAS)[(Q)*32 + sub*16 + lo];                                            \
        f32x4 a0 = zz4, a1 = zz4;                                                           \
        _Pragma("unroll") for (int kt = 0; kt < 4; ++kt) {                                  \
            short8 Bf = *(const short8*)&smem[(UBASE) + (sub*16+lo)*136 + kt*32 + hi*8];    \
            a0 = MFMA((FRAG)[0][kt], Bf, a0); a1 = MFMA((FRAG)[1][kt], Bf, a1); }           \
        _Pragma("unroll") for (int e = 0; e < 4; ++e) {                                     \
            float v0 = a0[e] + bb, v1 = a1[e] + bb;                                         \
            if (RELU) { v0 = fmaxf(v0, 0.f); v1 = fmaxf(v1, 0.f); }                         \
            S[(4*hi+e)*40 + sub*16 + lo]      = f2bf(v0);                                   \
            S[(16+4*hi+e)*40 + sub*16 + lo]   = f2bf(v1); }                                 \
    } } while (0)

#define AFRAG_READ(DST, Q) do {                                        \
    (DST)[0][Q] = *(const short8*)&S[lo*40 + hi*8];                    \
    (DST)[1][Q] = *(const short8*)&S[(16+lo)*40 + hi*8]; } while (0)

// one GRU output-column group JJ (16 cols): gi + gh + elementwise -> strip half (JJ&1)
#define GRU_J(JJ) do {                                                                      \
    const int ihB = G_BASE + (2*((JJ)&3))*6656;                                             \
    const int hhB = ihB + 6656;                                                             \
    const int j0 = (JJ)*16;                                                                 \
    const float bir = b_ih[j0+lo], biz = b_ih[128+j0+lo], bin = b_ih[256+j0+lo];            \
    const float bhr = b_hh[j0+lo], bhz = b_hh[128+j0+lo], bhn = b_hh[256+j0+lo];            \
    f32x4 accI[3][2], accH[3][2];                                                           \
    _Pragma("unroll") for (int g = 0; g < 3; ++g) {                                         \
        accI[g][0]=zz4; accI[g][1]=zz4; accH[g][0]=zz4; accH[g][1]=zz4;                     \
        _Pragma("unroll") for (int kt = 0; kt < 4; ++kt) {                                  \
            short8 Bi = *(const short8*)&smem[ihB + (g*16+lo)*136 + kt*32 + hi*8];          \
            accI[g][0] = MFMA(xa[0][kt], Bi, accI[g][0]);                                   \
            accI[g][1] = MFMA(xa[1][kt], Bi, accI[g][1]);                                   \
            short8 Bh = *(const short8*)&smem[hhB + (g*16+lo)*136 + kt*32 + hi*8];          \
            accH[g][0] = MFMA(ha[0][kt], Bh, accH[g][0]);                                   \
            accH[g][1] = MFMA(ha[1][kt], Bh, accH[g][1]);                                   \
        }                                                                                   \
    }                                                                                       \
    _Pragma("unroll") for (int rt = 0; rt < 2; ++rt)                                        \
    _Pragma("unroll") for (int p = 0; p < 2; ++p) {                                         \
        unsigned hp = h0d[JJ][rt][p];                                                       \
        float h0a = bf2f((short)(hp & 0xffffu));                                            \
        float h0b = bf2f((short)(hp >> 16));                                                \
        int e = 2*p;                                                                        \
        { float rg = fsigmoid(accI[0][rt][e] + bir + accH[0][rt][e] + bhr);                 \
          float zg = fsigmoid(accI[1][rt][e] + biz + accH[1][rt][e] + bhz);                 \
          float ng = ftanh(accI[2][rt][e] + bin + rg*(accH[2][rt][e] + bhn));               \
          S[(rt*16 + 4*hi + e)*40 + ((JJ)&1)*16 + lo] = f2bf((1.f-zg)*ng + zg*h0a); }       \
        { float rg = fsigmoid(accI[0][rt][e+1] + bir + accH[0][rt][e+1] + bhr);             \
          float zg = fsigmoid(accI[1][rt][e+1] + biz + accH[1][rt][e+1] + bhz);             \
          float ng = ftanh(accI[2][rt][e+1] + bin + rg*(accH[2][rt][e+1] + bhn));           \
          S[(rt*16 + 4*hi + e+1)*40 + ((JJ)&1)*16 + lo] = f2bf((1.f-zg)*ng + zg*h0b); }     \
    }                                                                                       \
} while (0)

// ---------------- main fused kernel: 512 threads (8 waves x 32 rows), grid 512 ----------------
// Superphase design: all weights LDS-resident per phase; waves free-run; 6 barriers total.
extern "C" __global__ __launch_bounds__(512, 1)
void gru_mfma(const float* __restrict__ z_t, const int* __restrict__ action,
              const float* __restrict__ hidden, const float* __restrict__ embed,
              const float* __restrict__ fuse_b,
              const float* __restrict__ b_ih, const float* __restrict__ b_hh,
              const float* __restrict__ ns_b1, const float* __restrict__ ns_b2,
              const float* __restrict__ rw_b1, const float* __restrict__ rw_W2, const float* __restrict__ rw_b2,
              const float* __restrict__ dn_b1, const float* __restrict__ dn_W2, const float* __restrict__ dn_b2,
              const short* __restrict__ ws, float* out)
{
    __shared__ __align__(16) short smem[76800];   // 153.6 KB -> 1 block/CU

    const int t    = threadIdx.x;
    const int lane = t & 63;
    const int w    = t >> 6;
    const int lo   = lane & 15;
    const int hi   = lane >> 4;
    const int R    = blockIdx.x * 256 + w * 32;   // wave's first batch row
    short* const S = &smem[STR_BASE + w * 1280];  // single per-wave strip [32][40]

    const f32x4 zz4 = {0.f, 0.f, 0.f, 0.f};

    auto store_hnew_strip = [&](int kt) {
        #pragma unroll
        for (int v = 0; v < 4; ++v) {
            int idx = v*64 + lane;
            int r = idx >> 3, c = (idx & 7) * 4;
            short4v s = *(const short4v*)&S[r*40 + c];
            f32x4 f = { bf2f(s[0]), bf2f(s[1]), bf2f(s[2]), bf2f(s[3]) };
            *(f32x4*)&out[HOFF + (size_t)(R + r)*128 + kt*32 + c] = f;
        }
    };
    auto store_z_strip = [&](int q) {
        #pragma unroll
        for (int v = 0; v < 4; ++v) {
            int idx = v*64 + lane;
            int r = idx >> 3, c = (idx & 7) * 4;
            short4v s = *(const short4v*)&S[r*40 + c];
            f32x4 f = { bf2f(s[0]), bf2f(s[1]), bf2f(s[2]), bf2f(s[3]) };
            *(f32x4*)&out[(size_t)(R + r)*64 + q*32 + c] = f;
        }
    };
    auto hpartial = [&](const float* W2, float acc) -> float {
        int rr = lane & 31;
        #pragma unroll
        for (int kk = 0; kk < 32; kk += 8) {
            short8 s = *(const short8*)&S[rr*40 + kk];
            f32x4 w0 = *(const f32x4*)&W2[kk];
            f32x4 w1 = *(const f32x4*)&W2[kk+4];
            acc += bf2f(s[0])*w0[0] + bf2f(s[1])*w0[1] + bf2f(s[2])*w0[2] + bf2f(s[3])*w0[3]
                 + bf2f(s[4])*w1[0] + bf2f(s[5])*w1[1] + bf2f(s[6])*w1[2] + bf2f(s[7])*w1[3];
        }
        return acc;
    };

    // ---- issue superphase-0 weight loads: fuse -> F, GRU j0..3 (8 units) -> G ----
    stage_lds<1664>(ws, &smem[0], t);
    stage_lds<6656>(ws + WS_GRU, &smem[G_BASE], t);

    // ---- A-fragments direct from global, f32 -> bf16 ----
    short8 fa[2][3];
    short8 ha[2][4];
    #pragma unroll
    for (int rt = 0; rt < 2; ++rt) {
        const int row = R + rt*16 + lo;
        #pragma unroll
        for (int kt = 0; kt < 2; ++kt) {
            f32x4 p0 = *(const f32x4*)&z_t[(size_t)row*64 + kt*32 + hi*8];
            f32x4 p1 = *(const f32x4*)&z_t[(size_t)row*64 + kt*32 + hi*8 + 4];
            fa[rt][kt] = packbf(p0, p1);
        }
        if (hi < 2) {
            int a = action[row];
            f32x4 e0 = *(const f32x4*)&embed[a*16 + hi*8];
            f32x4 e1 = *(const f32x4*)&embed[a*16 + hi*8 + 4];
            fa[rt][2] = packbf(e0, e1);
        } else {
            short8 z8 = {0,0,0,0,0,0,0,0};
            fa[rt][2] = z8;
        }
        #pragma unroll
        for (int kt = 0; kt < 4; ++kt) {
            f32x4 p0 = *(const f32x4*)&hidden[(size_t)row*128 + kt*32 + hi*8];
            f32x4 p1 = *(const f32x4*)&hidden[(size_t)row*128 + kt*32 + hi*8 + 4];
            ha[rt][kt] = packbf(p0, p1);
        }
    }
    float fbv[8];
    #pragma unroll
    for (int ct = 0; ct < 8; ++ct) fbv[ct] = fuse_b[ct*16 + lo];

    // ---- h0 D-layout values via sequential strip transposes (wave-private) ----
    unsigned h0d[8][2][2];
    #pragma unroll
    for (int kt = 0; kt < 4; ++kt) {
        *(short8*)&S[lo*40 + hi*8]        = ha[0][kt];
        *(short8*)&S[(16 + lo)*40 + hi*8] = ha[1][kt];
        #pragma unroll
        for (int c = 0; c < 2; ++c) {
            int j = 2*kt + c;
            #pragma unroll
            for (int rt = 0; rt < 2; ++rt)
                #pragma unroll
                for (int p = 0; p < 2; ++p) {
                    unsigned a = (unsigned short)S[(rt*16 + 4*hi + 2*p    )*40 + c*16 + lo];
                    unsigned b = (unsigned short)S[(rt*16 + 4*hi + 2*p + 1)*40 + c*16 + lo];
                    h0d[j][rt][p] = a | (b << 16);
                }
        }
    }
    __syncthreads();                       // B1: fuse + GRU group0 resident

    // ---- fuse: x = relu(F @ fuse_W^T + b), all weights resident, strip sequential ----
    short8 xa[2][4];
    #pragma unroll
    for (int kt = 0; kt < 4; ++kt) {
        #pragma unroll
        for (int c = 0; c < 2; ++c) {
            int ct = kt*2 + c;
            f32x4 a0 = zz4, a1 = zz4;
            #pragma unroll
            for (int fk = 0; fk < 3; ++fk) {
                short8 B = *(const short8*)&smem[(ct*16 + lo)*104 + fk*32 + hi*8];
                a0 = MFMA(fa[0][fk], B, a0);
                a1 = MFMA(fa[1][fk], B, a1);
            }
            #pragma unroll
            for (int e = 0; e < 4; ++e) {
                S[(4*hi + e)*40 + c*16 + lo]      = f2bf(fmaxf(a0[e] + fbv[ct], 0.f));
                S[(16 + 4*hi + e)*40 + c*16 + lo] = f2bf(fmaxf(a1[e] + fbv[ct], 0.f));
            }
        }
        AFRAG_READ(xa, kt);
    }

    // ---- GRU group 0 (j=0..3): barrier-free ----
    short8 hfa[2][4];
    GRU_J(0);
    GRU_J(1); AFRAG_READ(hfa, 0); store_hnew_strip(0);
    GRU_J(2);
    GRU_J(3); AFRAG_READ(hfa, 1); store_hnew_strip(1);

    __syncthreads();                       // B2: all waves done reading G group0
    stage_lds<6656>(ws + WS_GRU + 8*6656, &smem[G_BASE], t);
    __syncthreads();                       // B3: group1 resident (implicit vmcnt0)

    // ---- GRU group 1 (j=4..7): barrier-free ----
    GRU_J(4);
    GRU_J(5); AFRAG_READ(hfa, 2); store_hnew_strip(2);
    GRU_J(6);
    GRU_J(7); AFRAG_READ(hfa, 3); store_hnew_strip(3);

    __syncthreads();                       // B4: all waves done reading G group1
    stage_lds<5440>(ws + WS_HEAD, &smem[G_BASE], t);   // all 10 head units
    __syncthreads();                       // B5: heads resident

    // ---- heads: barrier-free, strip sequential ----
    short8 ta[2][4];
    HEAD_GEMM(hfa, ns_b1, 0, G_BASE + 0*4352, true);  AFRAG_READ(ta, 0);
    HEAD_GEMM(hfa, ns_b1, 1, G_BASE + 1*4352, true);  AFRAG_READ(ta, 1);
    HEAD_GEMM(hfa, ns_b1, 2, G_BASE + 2*4352, true);  AFRAG_READ(ta, 2);
    HEAD_GEMM(hfa, ns_b1, 3, G_BASE + 3*4352, true);  AFRAG_READ(ta, 3);
    HEAD_GEMM(ta,  ns_b2, 0, G_BASE + 4*4352, false); store_z_strip(0);
    HEAD_GEMM(ta,  ns_b2, 1, G_BASE + 5*4352, false); store_z_strip(1);

    float racc = rw_b2[0];
    HEAD_GEMM(hfa, rw_b1, 0, G_BASE + 6*4352, true);  racc = hpartial(rw_W2, racc);
    HEAD_GEMM(hfa, rw_b1, 1, G_BASE + 7*4352, true);  racc = hpartial(rw_W2 + 32, racc);
    if (lane < 32) out[(size_t)BATCH*64 + R + (lane & 31)] = racc;

    float dacc = dn_b2[0];
    HEAD_GEMM(hfa, dn_b1, 0, G_BASE + 8*4352, true);  dacc = hpartial(dn_W2, dacc);
    HEAD_GEMM(hfa, dn_b1, 1, G_BASE + 9*4352, true);  dacc = hpartial(dn_W2 + 32, dacc);
    if (lane < 32) out[(size_t)BATCH*65 + R + (lane & 31)] = dacc;
}

extern "C" void kernel_launch(void* const* d_in, const int* in_sizes, int n_in,
                              void* d_out, int out_size, void* d_ws, size_t ws_size,
                              hipStream_t stream) {
    const float* z_t    = (const float*)d_in[0];
    const int*   action = (const int*)  d_in[1];
    const float* hidden = (const float*)d_in[2];
    const float* embed  = (const float*)d_in[3];
    const float* fuse_W = (const float*)d_in[4];
    const float* fuse_b = (const float*)d_in[5];
    const float* W_ih   = (const float*)d_in[6];
    const float* W_hh   = (const float*)d_in[7];
    const float* b_ih   = (const float*)d_in[8];
    const float* b_hh   = (const float*)d_in[9];
    const float* ns_W1  = (const float*)d_in[10];
    const float* ns_b1  = (const float*)d_in[11];
    const float* ns_W2  = (const float*)d_in[12];
    const float* ns_b2  = (const float*)d_in[13];
    const float* rw_W1  = (const float*)d_in[14];
    const float* rw_b1  = (const float*)d_in[15];
    const float* rw_W2  = (const float*)d_in[16];
    const float* rw_b2  = (const float*)d_in[17];
    const float* dn_W1  = (const float*)d_in[18];
    const float* dn_b1  = (const float*)d_in[19];
    const float* dn_W2  = (const float*)d_in[20];
    const float* dn_b2  = (const float*)d_in[21];
    float* out = (float*)d_out;
    short* ws  = (short*)d_ws;

    hipLaunchKernelGGL(prep_weights, dim3((WS_ELEMS + 255) / 256), dim3(256), 0, stream,
                       fuse_W, W_ih, W_hh, ns_W1, ns_W2, rw_W1, dn_W1, ws);

    hipLaunchKernelGGL(gru_mfma, dim3(BATCH / 256), dim3(512), 0, stream,
                       z_t, action, hidden, embed,
                       fuse_b, b_ih, b_hh, ns_b1, ns_b2,
                       rw_b1, rw_W2, rw_b2, dn_b1, dn_W2, dn_b2,
                       ws, out);
}